// Round 3
// baseline (146.953 us; speedup 1.0000x reference)
//
#include <hip/hip_runtime.h>
#include <hip/hip_bf16.h>
#include <stdint.h>

// Problem constants (fixed by setup_inputs):
//   features (B=128, U=100000) f32; positions (U,2) f32; neighborhoods (NN=100, K=500) i32
//   N_RUNS=10, choice = jax.random.randint(key(42), (10,), 0, 100)  -> host Threefry
#define U_DIM 100000
#define B_DIM 128
#define K_DIM 500
#define NRUNS 10
#define KPAD  512
#define TILE  32
#define NTILES 16                                // ceil(500/32) over KPAD rows
#define NTILEPAIRS (NTILES * (NTILES + 1) / 2)   // 136 per run

typedef __attribute__((ext_vector_type(8))) short short8;   // 8 bf16 (4 VGPRs)
typedef __attribute__((ext_vector_type(4))) float f32x4;    // MFMA C/D

struct Args { int c[NRUNS]; float w[NRUNS]; int ru; };

// ---------------------------------------------------------------------------
// Kernel 1: per (unique-run r, k) wave: gather feature column, fused mean/var
// reduction (S, SS), store normalized bf16 row [k][b]. Pad rows 500..511 are
// zero-filled so no garbage bf16 ever enters an MFMA. Thread 0 also zeroes
// the done-counter used by kernel 2's fused finalize (ordered by the kernel
// boundary on the same stream).
// ---------------------------------------------------------------------------
__global__ __launch_bounds__(256) void prep_kernel(
    const float* __restrict__ feat, const float* __restrict__ pos,
    const int* __restrict__ neigh, __hip_bfloat16* __restrict__ xnb,
    float2* __restrict__ npos, unsigned* __restrict__ done_ctr, Args a)
{
  int gw   = (blockIdx.x * 256 + threadIdx.x) >> 6;   // global wave id
  int lane = threadIdx.x & 63;
  if (blockIdx.x == 0 && threadIdx.x == 0) *done_ctr = 0u;
  if (gw >= a.ru * KPAD) return;
  int r = gw >> 9;                           // gw / KPAD
  int k = gw & (KPAD - 1);

  size_t base = ((size_t)r * KPAD + k) * B_DIM;
  if (k >= K_DIM) {                          // zero-fill pad rows (poison-proof)
    xnb[base + lane]      = __float2bfloat16(0.0f);
    xnb[base + lane + 64] = __float2bfloat16(0.0f);
    return;
  }

  int ind = neigh[a.c[r] * K_DIM + k];
  float f0 = feat[(size_t)lane        * U_DIM + ind];
  float f1 = feat[(size_t)(lane + 64) * U_DIM + ind];

  float s  = f0 + f1;
  float ss = f0 * f0 + f1 * f1;
  #pragma unroll
  for (int off = 32; off; off >>= 1) {       // single fused chain for both sums
    s  += __shfl_xor(s,  off);
    ss += __shfl_xor(ss, off);
  }
  float mean = s * (1.0f / 128.0f);
  float q    = ss - s * mean;                // sum (x-mean)^2
  float inv  = rsqrtf(q);

  xnb[base + lane]      = __float2bfloat16((f0 - mean) * inv);
  xnb[base + lane + 64] = __float2bfloat16((f1 - mean) * inv);
  if (lane == 0) npos[r * KPAD + k] = make_float2(pos[2 * ind], pos[2 * ind + 1]);
}

// ---------------------------------------------------------------------------
// Kernel 2: one WAVE per 32x32 lower-triangle tile pair (136 pairs/run).
// corr via mfma_f32_16x16x32_bf16, fragments straight from global (L2/L3-hot,
// no LDS, no barriers). Per-wave Pearson partials shuffle-reduced into a
// private part[] slot. FUSED FINALIZE: the last wave to finish (device-scope
// counter + fences) deterministically reduces all slots in double and writes
// the weighted mean — removes the third dispatch entirely.
// ---------------------------------------------------------------------------
__global__ __launch_bounds__(256) void pair_kernel(
    const __hip_bfloat16* __restrict__ xnb, const float2* __restrict__ npos,
    float* __restrict__ part, float* __restrict__ out,
    unsigned* __restrict__ done_ctr, Args a)
{
  int gw   = (blockIdx.x * 256 + threadIdx.x) >> 6;
  int lane = threadIdx.x & 63;
  int total = a.ru * NTILEPAIRS;
  if (gw >= total) return;

  int r = gw / NTILEPAIRS;
  int p = gw - r * NTILEPAIRS;               // p = ti*(ti+1)/2 + tj, ti >= tj
  // closed-form triangular decode (exact for p < 2^23 after fixup)
  int ti = (int)((sqrtf(8.0f * (float)p + 1.0f) - 1.0f) * 0.5f);
  while ((ti + 1) * (ti + 2) / 2 <= p) ti++;
  while (ti * (ti + 1) / 2 > p) ti--;
  int tj = p - ti * (ti + 1) / 2;
  int i0 = ti * TILE, j0 = tj * TILE;

  const __hip_bfloat16* xr = xnb + (size_t)r * KPAD * B_DIM;
  int quad = lane >> 4, l16 = lane & 15;

  f32x4 acc00 = {}, acc01 = {}, acc10 = {}, acc11 = {};
  #pragma unroll
  for (int kk = 0; kk < 4; kk++) {
    int kb = kk * 32 + quad * 8;
    short8 a0 = *(const short8*)(xr + (size_t)(i0 + l16)      * B_DIM + kb);
    short8 a1 = *(const short8*)(xr + (size_t)(i0 + 16 + l16) * B_DIM + kb);
    short8 b0 = *(const short8*)(xr + (size_t)(j0 + l16)      * B_DIM + kb);
    short8 b1 = *(const short8*)(xr + (size_t)(j0 + 16 + l16) * B_DIM + kb);
    acc00 = __builtin_amdgcn_mfma_f32_16x16x32_bf16(a0, b0, acc00, 0, 0, 0);
    acc01 = __builtin_amdgcn_mfma_f32_16x16x32_bf16(a0, b1, acc01, 0, 0, 0);
    acc10 = __builtin_amdgcn_mfma_f32_16x16x32_bf16(a1, b0, acc10, 0, 0, 0);
    acc11 = __builtin_amdgcn_mfma_f32_16x16x32_bf16(a1, b1, acc11, 0, 0, 0);
  }

  // C/D layout: col = lane&15, row = quad*4 + reg (m89/m91-verified)
  const float2* pr = npos + r * KPAD;
  float sa = 0.f, sb = 0.f, saa = 0.f, sbb = 0.f, sab = 0.f;
  int gj0v = j0 + l16, gj1v = j0 + 16 + l16;
  float2 pj0 = pr[(gj0v < K_DIM) ? gj0v : 0];
  float2 pj1 = pr[(gj1v < K_DIM) ? gj1v : 0];

  #pragma unroll
  for (int tis = 0; tis < 2; tis++) {
    #pragma unroll
    for (int reg = 0; reg < 4; reg++) {
      int gi = i0 + tis * 16 + quad * 4 + reg;
      if (gi >= K_DIM) continue;
      float2 pi = pr[gi];
      if (gj0v < K_DIM && gi > gj0v) {
        float resp = tis ? acc10[reg] : acc00[reg];
        float dx = pi.x - pj0.x, dy = pi.y - pj0.y;
        float ds = 1.0f / (sqrtf(dx * dx + dy * dy) + 1.0f);
        sa += resp; sb += ds; saa += resp * resp; sbb += ds * ds; sab += resp * ds;
      }
      if (gj1v < K_DIM && gi > gj1v) {
        float resp = tis ? acc11[reg] : acc01[reg];
        float dx = pi.x - pj1.x, dy = pi.y - pj1.y;
        float ds = 1.0f / (sqrtf(dx * dx + dy * dy) + 1.0f);
        sa += resp; sb += ds; saa += resp * resp; sbb += ds * ds; sab += resp * ds;
      }
    }
  }

  #pragma unroll
  for (int off = 32; off; off >>= 1) {
    sa  += __shfl_xor(sa,  off);
    sb  += __shfl_xor(sb,  off);
    saa += __shfl_xor(saa, off);
    sbb += __shfl_xor(sbb, off);
    sab += __shfl_xor(sab, off);
  }
  if (lane == 0) {
    float* slot = part + (size_t)gw * 5;     // private slot: zero contention
    slot[0] = sa; slot[1] = sb; slot[2] = saa; slot[3] = sbb; slot[4] = sab;
  }

  // ---- fused finalize: last wave through the counter does the reduction ----
  __threadfence();                           // release our slot device-wide
  unsigned old = 0;
  if (lane == 0) old = atomicAdd(done_ctr, 1u);
  old = __shfl(old, 0);
  if (old != (unsigned)(total - 1)) return;

  __threadfence();                           // acquire all other slots
  double tloss = 0.0;
  for (int rr = 0; rr < a.ru; rr++) {
    double v[5] = {0, 0, 0, 0, 0};
    for (int pp = lane; pp < NTILEPAIRS; pp += 64) {
      const float* slot = part + ((size_t)rr * NTILEPAIRS + pp) * 5;
      #pragma unroll
      for (int i = 0; i < 5; i++) v[i] += (double)slot[i];
    }
    #pragma unroll
    for (int off = 32; off; off >>= 1) {
      #pragma unroll
      for (int i = 0; i < 5; i++) v[i] += __shfl_xor(v[i], off);
    }
    if (lane == 0) {
      const double n = (double)(K_DIM * (K_DIM - 1) / 2);   // 124750
      double cov = v[4] - v[0] * v[1] / n;
      double va  = v[2] - v[0] * v[0] / n;
      double vb  = v[3] - v[1] * v[1] / n;
      tloss += (double)a.w[rr] * (1.0 - cov / sqrt(va * vb)) * 0.5;
    }
  }
  if (lane == 0) out[0] = (float)(tloss / NRUNS);
}

// ---------------------------------------------------------------------------
// Host: JAX Threefry-2x32 to reproduce choice = randint(key(42), (10,), 0, 100)
// ---------------------------------------------------------------------------
static inline uint32_t rotl32_host(uint32_t x, int r) { return (x << r) | (x >> (32 - r)); }

static void tf2x32(uint32_t k0, uint32_t k1, uint32_t c0, uint32_t c1,
                   uint32_t& o0, uint32_t& o1)
{
  const uint32_t rots[2][4] = {{13, 15, 26, 6}, {17, 29, 16, 24}};
  uint32_t ks[3] = {k0, k1, k0 ^ k1 ^ 0x1BD11BDAu};
  uint32_t x0 = c0 + ks[0], x1 = c1 + ks[1];
  for (int i = 0; i < 5; i++) {
    const uint32_t* rr = rots[i & 1];
    for (int j = 0; j < 4; j++) {
      x0 += x1;
      x1 = rotl32_host(x1, (int)rr[j]);
      x1 ^= x0;
    }
    x0 += ks[(i + 1) % 3];
    x1 += ks[(i + 2) % 3] + (uint32_t)(i + 1);
  }
  o0 = x0; o1 = x1;
}

extern "C" void kernel_launch(void* const* d_in, const int* in_sizes, int n_in,
                              void* d_out, int out_size, void* d_ws, size_t ws_size,
                              hipStream_t stream)
{
  const float* feat  = (const float*)d_in[0];
  const float* pos   = (const float*)d_in[1];
  const int*   neigh = (const int*)d_in[2];
  float* out = (float*)d_out;

  // --- reproduce jax.random.randint(jax.random.key(42), (10,), 0, 100) ---
  uint32_t A0, B0, A1, B1;
  tf2x32(0u, 42u, 0u, 2u, A0, B0);
  tf2x32(0u, 42u, 1u, 3u, A1, B1);
  uint32_t hi[NRUNS], lo[NRUNS];
  for (int e = 0; e < 5; e++) {
    uint32_t h0, h1, l0, l1;
    tf2x32(A0, A1, (uint32_t)e, (uint32_t)(e + 5), h0, h1);
    hi[e] = h0; hi[e + 5] = h1;
    tf2x32(B0, B1, (uint32_t)e, (uint32_t)(e + 5), l0, l1);
    lo[e] = l0; lo[e + 5] = l1;
  }

  // --- dedupe duplicate choices: identical run => weight instead of recompute
  Args ar;
  for (int e = 0; e < NRUNS; e++) { ar.c[e] = 0; ar.w[e] = 0.0f; }
  int ru = 0;
  for (int e = 0; e < NRUNS; e++) {
    // span=100: multiplier = (2^16 % 100)^2 % 100 = 96
    int cv = (int)(((hi[e] % 100u) * 96u + (lo[e] % 100u)) % 100u);
    int f = -1;
    for (int u = 0; u < ru; u++) if (ar.c[u] == cv) { f = u; break; }
    if (f >= 0) ar.w[f] += 1.0f;
    else { ar.c[ru] = cv; ar.w[ru] = 1.0f; ru++; }
  }
  ar.ru = ru;

  // --- workspace layout ---
  char* ws = (char*)d_ws;
  __hip_bfloat16* xnb = (__hip_bfloat16*)ws;                 // 10*512*128 bf16 = 1.31 MB
  size_t off0 = (size_t)NRUNS * KPAD * B_DIM * sizeof(__hip_bfloat16);
  float2* npos = (float2*)(ws + off0);                       // 10*512 float2 = 40 KB
  size_t off1 = off0 + (size_t)NRUNS * KPAD * sizeof(float2);
  float*  part = (float*)(ws + off1);                        // <=1360*5 f32
  unsigned* done_ctr = (unsigned*)(ws + off1 + (size_t)NRUNS * NTILEPAIRS * 5 * sizeof(float));

  int prep_waves = ru * KPAD;                 // 1 wave per (run, k) incl. pad
  int pair_waves = ru * NTILEPAIRS;           // 1 wave per 32x32 tile pair
  prep_kernel<<<dim3((prep_waves + 3) / 4), 256, 0, stream>>>(feat, pos, neigh, xnb, npos, done_ctr, ar);
  pair_kernel<<<dim3((pair_waves + 3) / 4), 256, 0, stream>>>(xnb, npos, part, out, done_ctr, ar);
}

// Round 4
// 102.976 us; speedup vs baseline: 1.4271x; 1.4271x over previous
//
#include <hip/hip_runtime.h>
#include <hip/hip_bf16.h>
#include <stdint.h>

// Problem constants (fixed by setup_inputs):
//   features (B=128, U=100000) f32; positions (U,2) f32; neighborhoods (NN=100, K=500) i32
//   N_RUNS=10, choice = jax.random.randint(key(42), (10,), 0, 100)  -> host Threefry
#define U_DIM 100000
#define B_DIM 128
#define K_DIM 500
#define NRUNS 10
#define KPAD  512
#define TILE  32
#define NTILES 16                                // ceil(500/32)
#define NTILEPAIRS (NTILES * (NTILES + 1) / 2)   // 136 per run

typedef __attribute__((ext_vector_type(8))) short short8;   // 8 bf16 (4 VGPRs)
typedef __attribute__((ext_vector_type(4))) float f32x4;    // MFMA C/D

struct Args { int c[NRUNS]; float w[NRUNS]; int ru; };

// ---------------------------------------------------------------------------
// Kernel 1: per (unique-run r, k) wave: gather feature column, fused mean/var
// reduction (S, SS), store normalized bf16 row [k][b]. Pad rows 500..511
// zero-filled (no poisoned bf16 enters an MFMA).
// NOTE: no device-scope fences anywhere — round 3 showed per-wave
// __threadfence() costs ~50 µs in L2 invalidation storms on gfx950.
// ---------------------------------------------------------------------------
__global__ __launch_bounds__(256) void prep_kernel(
    const float* __restrict__ feat, const float* __restrict__ pos,
    const int* __restrict__ neigh, __hip_bfloat16* __restrict__ xnb,
    float2* __restrict__ npos, Args a)
{
  int gw   = (blockIdx.x * 256 + threadIdx.x) >> 6;   // global wave id
  int lane = threadIdx.x & 63;
  if (gw >= a.ru * KPAD) return;
  int r = gw >> 9;                           // gw / KPAD
  int k = gw & (KPAD - 1);

  size_t base = ((size_t)r * KPAD + k) * B_DIM;
  if (k >= K_DIM) {                          // zero-fill pad rows
    xnb[base + lane]      = __float2bfloat16(0.0f);
    xnb[base + lane + 64] = __float2bfloat16(0.0f);
    return;
  }

  int ind = neigh[a.c[r] * K_DIM + k];
  float f0 = feat[(size_t)lane        * U_DIM + ind];
  float f1 = feat[(size_t)(lane + 64) * U_DIM + ind];

  float s  = f0 + f1;
  float ss = f0 * f0 + f1 * f1;
  #pragma unroll
  for (int off = 32; off; off >>= 1) {       // single fused chain for both sums
    s  += __shfl_xor(s,  off);
    ss += __shfl_xor(ss, off);
  }
  float mean = s * (1.0f / 128.0f);
  float q    = ss - s * mean;                // sum (x-mean)^2
  float inv  = rsqrtf(q);

  xnb[base + lane]      = __float2bfloat16((f0 - mean) * inv);
  xnb[base + lane + 64] = __float2bfloat16((f1 - mean) * inv);
  if (lane == 0) npos[r * KPAD + k] = make_float2(pos[2 * ind], pos[2 * ind + 1]);
}

// ---------------------------------------------------------------------------
// Kernel 2: one WAVE per 32x32 lower-triangle tile pair (136 pairs/run).
// corr via mfma_f32_16x16x32_bf16, fragments straight from global (L2/L3-hot,
// no LDS, no barriers, no atomics, no fences). Per-wave Pearson partials
// shuffle-reduced, stored to a private part[] slot.
// ---------------------------------------------------------------------------
__global__ __launch_bounds__(256) void pair_kernel(
    const __hip_bfloat16* __restrict__ xnb, const float2* __restrict__ npos,
    float* __restrict__ part, Args a)
{
  int gw   = (blockIdx.x * 256 + threadIdx.x) >> 6;
  int lane = threadIdx.x & 63;
  if (gw >= a.ru * NTILEPAIRS) return;

  int r = gw / NTILEPAIRS;
  int p = gw - r * NTILEPAIRS;               // p = ti*(ti+1)/2 + tj, ti >= tj
  // closed-form triangular decode + fixup (replaces 31-iter serial loop)
  int ti = (int)((sqrtf(8.0f * (float)p + 1.0f) - 1.0f) * 0.5f);
  while ((ti + 1) * (ti + 2) / 2 <= p) ti++;
  while (ti * (ti + 1) / 2 > p) ti--;
  int tj = p - ti * (ti + 1) / 2;
  int i0 = ti * TILE, j0 = tj * TILE;

  const __hip_bfloat16* xr = xnb + (size_t)r * KPAD * B_DIM;
  int quad = lane >> 4, l16 = lane & 15;

  f32x4 acc00 = {}, acc01 = {}, acc10 = {}, acc11 = {};
  #pragma unroll
  for (int kk = 0; kk < 4; kk++) {
    int kb = kk * 32 + quad * 8;
    short8 a0 = *(const short8*)(xr + (size_t)(i0 + l16)      * B_DIM + kb);
    short8 a1 = *(const short8*)(xr + (size_t)(i0 + 16 + l16) * B_DIM + kb);
    short8 b0 = *(const short8*)(xr + (size_t)(j0 + l16)      * B_DIM + kb);
    short8 b1 = *(const short8*)(xr + (size_t)(j0 + 16 + l16) * B_DIM + kb);
    acc00 = __builtin_amdgcn_mfma_f32_16x16x32_bf16(a0, b0, acc00, 0, 0, 0);
    acc01 = __builtin_amdgcn_mfma_f32_16x16x32_bf16(a0, b1, acc01, 0, 0, 0);
    acc10 = __builtin_amdgcn_mfma_f32_16x16x32_bf16(a1, b0, acc10, 0, 0, 0);
    acc11 = __builtin_amdgcn_mfma_f32_16x16x32_bf16(a1, b1, acc11, 0, 0, 0);
  }

  // C/D layout: col = lane&15, row = quad*4 + reg (m89/m91-verified)
  const float2* pr = npos + r * KPAD;
  float sa = 0.f, sb = 0.f, saa = 0.f, sbb = 0.f, sab = 0.f;
  int gj0v = j0 + l16, gj1v = j0 + 16 + l16;
  float2 pj0 = pr[(gj0v < K_DIM) ? gj0v : 0];
  float2 pj1 = pr[(gj1v < K_DIM) ? gj1v : 0];

  #pragma unroll
  for (int tis = 0; tis < 2; tis++) {
    #pragma unroll
    for (int reg = 0; reg < 4; reg++) {
      int gi = i0 + tis * 16 + quad * 4 + reg;
      if (gi >= K_DIM) continue;
      float2 pi = pr[gi];
      if (gj0v < K_DIM && gi > gj0v) {
        float resp = tis ? acc10[reg] : acc00[reg];
        float dx = pi.x - pj0.x, dy = pi.y - pj0.y;
        float ds = 1.0f / (sqrtf(dx * dx + dy * dy) + 1.0f);
        sa += resp; sb += ds; saa += resp * resp; sbb += ds * ds; sab += resp * ds;
      }
      if (gj1v < K_DIM && gi > gj1v) {
        float resp = tis ? acc11[reg] : acc01[reg];
        float dx = pi.x - pj1.x, dy = pi.y - pj1.y;
        float ds = 1.0f / (sqrtf(dx * dx + dy * dy) + 1.0f);
        sa += resp; sb += ds; saa += resp * resp; sbb += ds * ds; sab += resp * ds;
      }
    }
  }

  #pragma unroll
  for (int off = 32; off; off >>= 1) {
    sa  += __shfl_xor(sa,  off);
    sb  += __shfl_xor(sb,  off);
    saa += __shfl_xor(saa, off);
    sbb += __shfl_xor(sbb, off);
    sab += __shfl_xor(sab, off);
  }

  if (lane == 0) {
    float* slot = part + (size_t)gw * 5;     // private slot: zero contention
    slot[0] = sa; slot[1] = sb; slot[2] = saa; slot[3] = sbb; slot[4] = sab;
  }
}

// ---------------------------------------------------------------------------
// Kernel 3: 1 block, 10 waves. Wave r reduces the 136 partial-sum slots of
// unique-run r in double, computes Pearson r -> weighted loss; thread 0
// averages over the original 10 runs (weights sum to 10).
// ---------------------------------------------------------------------------
__global__ __launch_bounds__(640) void finalize_kernel(
    const float* __restrict__ part, float* __restrict__ out, Args a)
{
  __shared__ double contrib[NRUNS];
  int wave = threadIdx.x >> 6;    // = unique-run index
  int lane = threadIdx.x & 63;

  if (wave < a.ru) {
    double v[5] = {0, 0, 0, 0, 0};
    for (int p = lane; p < NTILEPAIRS; p += 64) {
      const float* slot = part + ((size_t)wave * NTILEPAIRS + p) * 5;
      #pragma unroll
      for (int i = 0; i < 5; i++) v[i] += (double)slot[i];
    }
    #pragma unroll
    for (int off = 32; off; off >>= 1) {
      #pragma unroll
      for (int i = 0; i < 5; i++) v[i] += __shfl_xor(v[i], off);
    }
    if (lane == 0) {
      const double n = (double)(K_DIM * (K_DIM - 1) / 2);   // 124750
      double cov = v[4] - v[0] * v[1] / n;
      double va  = v[2] - v[0] * v[0] / n;
      double vb  = v[3] - v[1] * v[1] / n;
      contrib[wave] = (double)a.w[wave] * (1.0 - cov / sqrt(va * vb)) * 0.5;
    }
  }
  __syncthreads();
  if (threadIdx.x == 0) {
    double total = 0.0;
    for (int r = 0; r < a.ru; r++) total += contrib[r];
    out[0] = (float)(total / NRUNS);
  }
}

// ---------------------------------------------------------------------------
// Host: JAX Threefry-2x32 to reproduce choice = randint(key(42), (10,), 0, 100)
// ---------------------------------------------------------------------------
static inline uint32_t rotl32_host(uint32_t x, int r) { return (x << r) | (x >> (32 - r)); }

static void tf2x32(uint32_t k0, uint32_t k1, uint32_t c0, uint32_t c1,
                   uint32_t& o0, uint32_t& o1)
{
  const uint32_t rots[2][4] = {{13, 15, 26, 6}, {17, 29, 16, 24}};
  uint32_t ks[3] = {k0, k1, k0 ^ k1 ^ 0x1BD11BDAu};
  uint32_t x0 = c0 + ks[0], x1 = c1 + ks[1];
  for (int i = 0; i < 5; i++) {
    const uint32_t* rr = rots[i & 1];
    for (int j = 0; j < 4; j++) {
      x0 += x1;
      x1 = rotl32_host(x1, (int)rr[j]);
      x1 ^= x0;
    }
    x0 += ks[(i + 1) % 3];
    x1 += ks[(i + 2) % 3] + (uint32_t)(i + 1);
  }
  o0 = x0; o1 = x1;
}

extern "C" void kernel_launch(void* const* d_in, const int* in_sizes, int n_in,
                              void* d_out, int out_size, void* d_ws, size_t ws_size,
                              hipStream_t stream)
{
  const float* feat  = (const float*)d_in[0];
  const float* pos   = (const float*)d_in[1];
  const int*   neigh = (const int*)d_in[2];
  float* out = (float*)d_out;

  // --- reproduce jax.random.randint(jax.random.key(42), (10,), 0, 100) ---
  uint32_t A0, B0, A1, B1;
  tf2x32(0u, 42u, 0u, 2u, A0, B0);
  tf2x32(0u, 42u, 1u, 3u, A1, B1);
  uint32_t hi[NRUNS], lo[NRUNS];
  for (int e = 0; e < 5; e++) {
    uint32_t h0, h1, l0, l1;
    tf2x32(A0, A1, (uint32_t)e, (uint32_t)(e + 5), h0, h1);
    hi[e] = h0; hi[e + 5] = h1;
    tf2x32(B0, B1, (uint32_t)e, (uint32_t)(e + 5), l0, l1);
    lo[e] = l0; lo[e + 5] = l1;
  }

  // --- dedupe duplicate choices: identical run => weight instead of recompute
  Args ar;
  for (int e = 0; e < NRUNS; e++) { ar.c[e] = 0; ar.w[e] = 0.0f; }
  int ru = 0;
  for (int e = 0; e < NRUNS; e++) {
    // span=100: multiplier = (2^16 % 100)^2 % 100 = 96
    int cv = (int)(((hi[e] % 100u) * 96u + (lo[e] % 100u)) % 100u);
    int f = -1;
    for (int u = 0; u < ru; u++) if (ar.c[u] == cv) { f = u; break; }
    if (f >= 0) ar.w[f] += 1.0f;
    else { ar.c[ru] = cv; ar.w[ru] = 1.0f; ru++; }
  }
  ar.ru = ru;

  // --- workspace layout ---
  char* ws = (char*)d_ws;
  __hip_bfloat16* xnb = (__hip_bfloat16*)ws;                 // 10*512*128 bf16 = 1.31 MB
  size_t off0 = (size_t)NRUNS * KPAD * B_DIM * sizeof(__hip_bfloat16);
  float2* npos = (float2*)(ws + off0);                       // 10*512 float2 = 40 KB
  float*  part = (float*)(ws + off0 + (size_t)NRUNS * KPAD * sizeof(float2));  // <=1360*5 f32

  int prep_waves = ru * KPAD;                 // 1 wave per (run, k) incl. pad
  int pair_waves = ru * NTILEPAIRS;           // 1 wave per 32x32 tile pair
  prep_kernel<<<dim3((prep_waves + 3) / 4), 256, 0, stream>>>(feat, pos, neigh, xnb, npos, ar);
  pair_kernel<<<dim3((pair_waves + 3) / 4), 256, 0, stream>>>(xnb, npos, part, ar);
  finalize_kernel<<<dim3(1), 640, 0, stream>>>(part, out, ar);
}